// Round 1
// baseline (166.301 us; speedup 1.0000x reference)
//
#include <hip/hip_runtime.h>

// Problem constants (match reference setup_inputs)
constexpr int   B = 32, E = 64, H = 128, W = 128, R = 13, D = 32;
constexpr float GAIN = 2.0f, BASELINE = 100.0f;
constexpr int   HALF = R / 2;           // 6

// native vector type so __builtin_nontemporal_store accepts it
typedef float f4_t __attribute__((ext_vector_type(4)));

// power v^p for p in 0..3, with 0^0 == 1
__device__ __forceinline__ float pw(float v, int p) {
    float r = 1.0f;
    if (p >= 1) r = v;
    if (p >= 2) r *= v;
    if (p >= 3) r *= v;
    return r;
}

// ---------------------------------------------------------------------------
// Fused kernel: one block per 32-row strip of one (b,e) output plane.
//   out[b,e,p] = (bg[b,p] + patch(p)) * GAIN + BASELINE
// Patch (13x13 cubic-spline PSF) is computed into LDS only when it overlaps
// this strip (block-uniform), then folded into the streaming store so every
// output pixel is written exactly once.  JAX .at[].add(mode='drop')
// semantics: negative indices wrap (+size); >=size dropped.  r0,c0 >= -6 so
// wrapped rows/cols land at >=122 (valid); high side is dropped.
// Stores are nontemporal: the 128 MiB output stream is write-once and would
// otherwise evict the L2-resident bg (2 MiB) + coeff (1.7 MB) working set.
// ---------------------------------------------------------------------------
__global__ __launch_bounds__(256)
void fused_kernel(const float* __restrict__ xyz,       // [B,E,3]
                  const float* __restrict__ n_photons, // [B,E]
                  const float* __restrict__ bg,        // [B,H,W]
                  const float* __restrict__ coeff,     // [D,R,R,4,4,4]
                  float* __restrict__ out)             // [B,E,H,W]
{
    const int bid = blockIdx.x;
    const int q   = bid & 3;           // quarter-plane strip (32 rows)
    const int be  = bid >> 2;          // emitter-plane id
    const int b   = be >> 6;           // frame  (/E)
    const int tid = threadIdx.x;
    const int r_base = q << 5;         // first row of this strip

    __shared__ float s_w[64];          // separable weights pz[a]*py[b]*px[c]
    __shared__ float s_patch[R * R];   // 13x13 PSF patch * n_photons

    // emitter parameters (broadcast loads, computed redundantly per thread)
    const float x = xyz[be * 3 + 0];
    const float y = xyz[be * 3 + 1];

    const float xf = floorf(x), yf = floorf(y);
    const int r0 = (int)yf - HALF;
    const int c0 = (int)xf - HALF;

    // block-uniform: does the patch's row set intersect [r_base, r_base+32)?
    // non-wrapped rows: max(r0,0)..min(r0+12,127); wrapped (r0<0): 128+r0..127
    bool need;
    {
        const int lo = max(r0, 0), hi = min(r0 + R - 1, H - 1);
        need = (lo <= r_base + 31) && (hi >= r_base);
        if (r0 < 0 && r_base + 31 >= H + r0) need = true;
    }

    if (need) {
        const float z  = xyz[be * 3 + 2];
        const float dx = x - xf, dy = y - yf;
        float zc = fminf(fmaxf(z, 0.0f), (float)(D - 1) - 1e-6f);
        const float zf = floorf(zc);
        const int   zi = (int)zf;
        const float dz = zc - zf;
        if (tid < 64) {
            const int a  = tid >> 4;
            const int bb = (tid >> 2) & 3;
            const int c  = tid & 3;
            s_w[tid] = pw(dz, a) * pw(dy, bb) * pw(dx, c);
        }
        __syncthreads();                       // block-uniform branch: legal
        if (tid < R * R) {
            const int pr = tid / R;
            const int pc = tid - pr * R;
            const float* cp = coeff + (((size_t)zi * R + pr) * R + pc) * 64;
            float acc = 0.0f;
            #pragma unroll
            for (int k = 0; k < 64; k += 4) {
                const f4_t cc = *(const f4_t*)(cp + k);
                acc += cc.x * s_w[k + 0];
                acc += cc.y * s_w[k + 1];
                acc += cc.z * s_w[k + 2];
                acc += cc.w * s_w[k + 3];
            }
            s_patch[tid] = acc * n_photons[be];
        }
        __syncthreads();
    }

    // stream the strip: 1024 float4 per block, 4 per thread, fully coalesced
    const f4_t* bgp  = (const f4_t*)(bg  + ((size_t)b  << 14)) + (q << 10);
    f4_t*       outp = (f4_t*)      (out + ((size_t)be << 14)) + (q << 10);

    #pragma unroll
    for (int j = 0; j < 4; ++j) {
        const int f = (j << 8) + tid;          // float4 index within strip
        f4_t v = bgp[f];
        if (need) {
            const int row = r_base + (f >> 5);
            int pr = row - r0;                              // direct
            if ((unsigned)pr >= (unsigned)R) pr = row - r0 - H;  // wrapped
            if ((unsigned)pr < (unsigned)R) {
                const float* prow = s_patch + pr * R;
                const int cb = (f & 31) << 2;               // first col of float4
                #pragma unroll
                for (int cmp = 0; cmp < 4; ++cmp) {
                    int pc = cb + cmp - c0;                 // direct
                    if ((unsigned)pc >= (unsigned)R) pc = cb + cmp - c0 - W;
                    if ((unsigned)pc < (unsigned)R) v[cmp] += prow[pc];
                }
            }
        }
        f4_t o;
        o.x = v.x * GAIN + BASELINE;
        o.y = v.y * GAIN + BASELINE;
        o.z = v.z * GAIN + BASELINE;
        o.w = v.w * GAIN + BASELINE;
        __builtin_nontemporal_store(o, outp + f);
    }
}

extern "C" void kernel_launch(void* const* d_in, const int* in_sizes, int n_in,
                              void* d_out, int out_size, void* d_ws, size_t ws_size,
                              hipStream_t stream) {
    const float* xyz       = (const float*)d_in[0];  // [B,E,3]
    const float* n_photons = (const float*)d_in[1];  // [B,E]
    const float* bg        = (const float*)d_in[2];  // [B,H,W]
    const float* coeff     = (const float*)d_in[3];  // [D,R,R,4,4,4]
    float* out = (float*)d_out;                      // [B,E,H,W]

    // one fused pass: 32*64 planes x 4 strips = 8192 blocks x 256 threads
    fused_kernel<<<dim3(B * E * 4), dim3(256), 0, stream>>>(
        xyz, n_photons, bg, coeff, out);
}